// Round 10
// baseline (27.898 us; speedup 1.0000x reference)
//
#include <hip/hip_runtime.h>
#include <math.h>

#define DIMQ 16
#define HID  128
#define SPB  32          // samples per block (8 waves; each wave owns ONE 16-h tile, all samples)
#define NTHREADS 512

typedef __attribute__((ext_vector_type(8))) short bf16x8;   // MFMA A/B frag (4 VGPRs)
typedef __attribute__((ext_vector_type(4))) short s16x4;    // packed b64 store
typedef __attribute__((ext_vector_type(4))) float f32x4;    // MFMA acc

// bf16 row strides (elements)
#define ASTR 280         // ABT[16][280]: [A^T | B^T], 560B row -> bank skew
#define USTR 280         // usp[32][280]: u at h'=0..127, -sp at h'=128..255
#define SSTR 136         // sst[32][136]: s values (v7-validated stride)

// LDS layout (bytes). Mscr overlays everything AFTER barrier #2.
#define OFF_ABT  0       // bf16[16][280] =  8960
#define OFF_USP  8960    // bf16[32][280] = 17920 -> 26880
#define OFF_SST  26880   // bf16[32][136] =  8704 -> 35584
#define OFF_MSCR 0       // f32 32*320 = 40960 (post-barrier-2 overlay)
#define LDS_BYTES 40960

__device__ __forceinline__ float bf2f(short s) {
    union { unsigned u; float f; } cv;
    cv.u = ((unsigned)(unsigned short)s) << 16;
    return cv.f;
}
__device__ __forceinline__ short f2bf(float f) {
    __bf16 h = (__bf16)f;
    return __builtin_bit_cast(short, h);
}
__device__ __forceinline__ bf16x8 pack8(float4 a, float4 b) {
    bf16x8 r;
    r[0] = f2bf(a.x); r[1] = f2bf(a.y); r[2] = f2bf(a.z); r[3] = f2bf(a.w);
    r[4] = f2bf(b.x); r[5] = f2bf(b.y); r[6] = f2bf(b.z); r[7] = f2bf(b.w);
    return r;
}
// XOR-swizzle inside each sample's 320-f32 M-scratch (v7-validated).
__device__ __forceinline__ int mswz(int s, int off) {
    return s * 320 + (off ^ ((s & 7) << 2));
}

__global__ __launch_bounds__(NTHREADS, 3)
void lag_accel_kernel(const float* __restrict__ y,    // [BATCH][32]
                      const float* __restrict__ W1,   // [128][32]
                      const float* __restrict__ b1,   // [128]
                      const float* __restrict__ w2,   // [128]
                      float* __restrict__ out)        // [BATCH][16]
{
    __shared__ __align__(16) char smem[LDS_BYTES];
    short* ABT = (short*)(smem + OFF_ABT);   // [16][280] bf16: [j][h]=A[h][j], [j][128+h]=B[h][j]
    short* usp = (short*)(smem + OFF_USP);   // [32][280] bf16: u / -sp
    short* sst = (short*)(smem + OFF_SST);   // [32][136] bf16: s

    const int tid = threadIdx.x;
    const long long s0 = (long long)blockIdx.x * SPB;

    const int wave = tid >> 6;
    const int lane = tid & 63;
    const int grp  = lane >> 4;      // MFMA quadrant (k-slice / D row-block)
    const int j    = lane & 15;      // MFMA m/n index
    const int ht   = wave;           // this wave's h-tile (h = 16*ht .. 16*ht+15)

    // ---- up-front register loads (global, L1/L2-hot; no LDS dependency) ----
    const int hrow = ht * 16 + j;
    const float4* wg = (const float4*)(W1 + hrow * 32);
    float4 w0 = wg[grp * 2], w1v_ = wg[grp * 2 + 1];             // aW: W1[hrow][8grp..+7]
    float4 xa = wg[(grp & 1) * 2], xb = wg[(grp & 1) * 2 + 1];   // aA source (grp>=2)
    const float4* yg0 = (const float4*)(y + (s0 + 0 * 16 + j) * 32 + (grp << 3));
    const float4* yg1 = (const float4*)(y + (s0 + 1 * 16 + j) * 32 + (grp << 3));
    float4 y00 = yg0[0], y01 = yg0[1];
    float4 y10 = yg1[0], y11 = yg1[1];
    float4 b1v = *(const float4*)&b1[ht * 16 + (grp << 2)];
    float4 w2v = *(const float4*)&w2[ht * 16 + (grp << 2)];

    // ---- ABT staging (only LDS staging left); visibility covered by barrier 1 ----
    for (int idx = tid; idx < HID * 32; idx += NTHREADS) {
        float v = W1[idx];
        int h = idx >> 5, k = idx & 31;
        short bv = f2bf(v);
        if (k < 16) ABT[k * ASTR + h] = bv;
        else        ABT[(k - 16) * ASTR + 128 + h] = bv;
    }

    // ---- z/aqd GEMM: z = [A|B].y + b1 and aqd = [0|A].y (K=32), per h-tile ----
    bf16x8 aW = pack8(w0, w1v_);
    bf16x8 aAf = pack8(xa, xb);
    bf16x8 aA;
#pragma unroll
    for (int e = 0; e < 8; ++e) aA[e] = (grp >= 2) ? aAf[e] : (short)0;

    f32x4 zacc[2], aacc[2];
    {
        f32x4 ci; ci[0] = b1v.x; ci[1] = b1v.y; ci[2] = b1v.z; ci[3] = b1v.w;
        f32x4 zf = {0.0f, 0.0f, 0.0f, 0.0f};
        bf16x8 yf0 = pack8(y00, y01);
        bf16x8 yf1 = pack8(y10, y11);
        zacc[0] = __builtin_amdgcn_mfma_f32_16x16x32_bf16(aW, yf0, ci, 0, 0, 0);
        zacc[1] = __builtin_amdgcn_mfma_f32_16x16x32_bf16(aW, yf1, ci, 0, 0, 0);
        aacc[0] = __builtin_amdgcn_mfma_f32_16x16x32_bf16(aA, yf0, zf, 0, 0, 0);
        aacc[1] = __builtin_amdgcn_mfma_f32_16x16x32_bf16(aA, yf1, zf, 0, 0, 0);
    }

    // ---- elementwise: t,u,s,sp per (h = 16ht+4grp+r, smp = 16st+j); stage bf16 ----
    const int h4 = ht * 16 + (grp << 2);
#define EWST(st)                                                         \
    {                                                                    \
        short su[4], sn[4], sv[4];                                       \
        _Pragma("unroll")                                                \
        for (int r = 0; r < 4; ++r) {                                    \
            float z  = zacc[st][r], aq = aacc[st][r];                    \
            float w2c = (r == 0) ? w2v.x : (r == 1) ? w2v.y               \
                       : (r == 2) ? w2v.z : w2v.w;                       \
            float e  = __expf(2.0f * z);                                 \
            float rr = 2.0f * __builtin_amdgcn_rcpf(e + 1.0f);           \
            float t  = 1.0f - rr;                                        \
            float u  = w2c * (rr * (2.0f - rr));                         \
            float s  = -2.0f * t * u;                                    \
            float sp = s * aq;                                           \
            su[r] = f2bf(u); sn[r] = f2bf(-sp); sv[r] = f2bf(s);         \
        }                                                                \
        const int smp2 = (st) * 16 + j;                                  \
        s16x4 pa = {su[0], su[1], su[2], su[3]};                         \
        s16x4 pb = {sn[0], sn[1], sn[2], sn[3]};                         \
        s16x4 pc = {sv[0], sv[1], sv[2], sv[3]};                         \
        *(s16x4*)&usp[smp2 * USTR + h4]       = pa;                      \
        *(s16x4*)&usp[smp2 * USTR + 128 + h4] = pb;                      \
        *(s16x4*)&sst[smp2 * SSTR + h4]       = pc;                      \
    }
    EWST(0)
    EWST(1)
#undef EWST

    __syncthreads();   // barrier 1: ABT staged + u/-sp/s staged by all h-tiles

    // ---- rhs GEMM (waves 0,1): rhs = [A^T|B^T].[u;-sp], K=256; D lands in solve layout ----
    f32x4 racc = {0.0f, 0.0f, 0.0f, 0.0f};
    if (wave < 2) {
#pragma unroll
        for (int kc = 0; kc < 8; ++kc) {
            bf16x8 af = *(const bf16x8*)&ABT[j * ASTR + (kc << 5) + (grp << 3)];
            bf16x8 bf = *(const bf16x8*)&usp[(wave * 16 + j) * USTR + (kc << 5) + (grp << 3)];
            racc = __builtin_amdgcn_mfma_f32_16x16x32_bf16(af, bf, racc, 0, 0, 0);
        }
    }

    // ---- M = I + B~^T diag(s) B~ via MFMA (v7-validated); wave's samples 4w..4w+3 ----
    f32x4 acc[4];
    {
        f32x4 ident;
#pragma unroll
        for (int r = 0; r < 4; ++r) ident[r] = ((grp << 2) + r == j) ? 1.0f : 0.0f;
#pragma unroll
        for (int gs = 0; gs < 4; ++gs) acc[gs] = ident;
    }
#pragma unroll
    for (int kc = 0; kc < 4; ++kc) {
        bf16x8 bfrag = *(const bf16x8*)&ABT[j * ASTR + 128 + (kc << 5) + (grp << 3)];
        float Bf[8];
#pragma unroll
        for (int e = 0; e < 8; ++e) Bf[e] = bf2f(bfrag[e]);
#pragma unroll
        for (int gs = 0; gs < 4; ++gs) {
            bf16x8 sfrag = *(const bf16x8*)&sst[(wave * 4 + gs) * SSTR + (kc << 5) + (grp << 3)];
            bf16x8 afrag;
#pragma unroll
            for (int e = 0; e < 8; ++e) afrag[e] = f2bf(bf2f(sfrag[e]) * Bf[e]);
            acc[gs] = __builtin_amdgcn_mfma_f32_16x16x32_bf16(afrag, bfrag, acc[gs], 0, 0, 0);
        }
    }

    __syncthreads();   // barrier 2: all GEMM reads of ABT/usp/sst done -> Mscr overlay

    float* Mscr = (float*)(smem + OFF_MSCR);
    // M symmetric: D(rows 4grp..4grp+3, col j) == M[j][4grp..4grp+3] -> one b128/sample.
#pragma unroll
    for (int gs = 0; gs < 4; ++gs) {
        float4 v;
        v.x = acc[gs][0]; v.y = acc[gs][1]; v.z = acc[gs][2]; v.w = acc[gs][3];
        *(float4*)&Mscr[mswz(wave * 4 + gs, j * 20 + (grp << 2))] = v;
    }

    __syncthreads();   // barrier 3: scratch complete

    // ---- solve (waves 0,1; 16 samples each; 4 lanes/sample, 4 rows/lane) ----
    if (wave >= 2) return;
    const int sl = lane & 15;            // sample within this wave's half
    const int rb = lane >> 4;            // row block (rows 4rb..4rb+3)
    const int s  = wave * 16 + sl;       // sample within block

    float M4[4][16], r4[4], d4[4];
#pragma unroll
    for (int r = 0; r < 4; ++r) {
        const int ro = (4 * rb + r) * 20;
        float4 v0 = *(const float4*)&Mscr[mswz(s, ro + 0)];
        float4 v1 = *(const float4*)&Mscr[mswz(s, ro + 4)];
        float4 v2 = *(const float4*)&Mscr[mswz(s, ro + 8)];
        float4 v3 = *(const float4*)&Mscr[mswz(s, ro + 12)];
        M4[r][0]=v0.x; M4[r][1]=v0.y; M4[r][2]=v0.z; M4[r][3]=v0.w;
        M4[r][4]=v1.x; M4[r][5]=v1.y; M4[r][6]=v1.z; M4[r][7]=v1.w;
        M4[r][8]=v2.x; M4[r][9]=v2.y; M4[r][10]=v2.z; M4[r][11]=v2.w;
        M4[r][12]=v3.x; M4[r][13]=v3.y; M4[r][14]=v3.z; M4[r][15]=v3.w;
        r4[r] = racc[r];                 // rhs already in the right lane/reg
        d4[r] = 1.0f;
    }

    // Gauss-Jordan, non-normalizing, triangular skip (v7-validated).
#pragma unroll
    for (int k = 0; k < 16; ++k) {
        const int src = sl + ((k >> 2) << 4);
        float piv = __shfl(M4[k & 3][k], src, 64);
        float rk  = __shfl(r4[k & 3], src, 64);
        float invp = __builtin_amdgcn_rcpf(piv);
        invp = invp * (2.0f - piv * invp);
        float f[4];
#pragma unroll
        for (int r = 0; r < 4; ++r) {
            float fr = M4[r][k] * invp;
            const bool isk = ((rb << 2) + r) == k;
            f[r]  = isk ? 0.0f : fr;
            d4[r] = isk ? piv : d4[r];
            r4[r] = fmaf(-f[r], rk, r4[r]);
        }
#pragma unroll
        for (int i = k + 1; i < 16; ++i) {
            float p = __shfl(M4[k & 3][i], src, 64);
            M4[0][i] = fmaf(-f[0], p, M4[0][i]);
            M4[1][i] = fmaf(-f[1], p, M4[1][i]);
            M4[2][i] = fmaf(-f[2], p, M4[2][i]);
            M4[3][i] = fmaf(-f[3], p, M4[3][i]);
        }
    }

    float4 xo;
    {
        float i0 = __builtin_amdgcn_rcpf(d4[0]); i0 = i0 * (2.0f - d4[0] * i0);
        float i1 = __builtin_amdgcn_rcpf(d4[1]); i1 = i1 * (2.0f - d4[1] * i1);
        float i2 = __builtin_amdgcn_rcpf(d4[2]); i2 = i2 * (2.0f - d4[2] * i2);
        float i3 = __builtin_amdgcn_rcpf(d4[3]); i3 = i3 * (2.0f - d4[3] * i3);
        xo.x = r4[0] * i0; xo.y = r4[1] * i1; xo.z = r4[2] * i2; xo.w = r4[3] * i3;
    }
    *(float4*)&out[(s0 + s) * DIMQ + (rb << 2)] = xo;
}

extern "C" void kernel_launch(void* const* d_in, const int* in_sizes, int n_in,
                              void* d_out, int out_size, void* d_ws, size_t ws_size,
                              hipStream_t stream) {
    const float* y  = (const float*)d_in[0];
    const float* W1 = (const float*)d_in[1];
    const float* b1 = (const float*)d_in[2];
    const float* w2 = (const float*)d_in[3];
    float* out = (float*)d_out;
    const int batch = in_sizes[0] / 32;          // 32768
    const int blocks = (batch + SPB - 1) / SPB;  // 1024
    lag_accel_kernel<<<blocks, NTHREADS, 0, stream>>>(y, W1, b1, w2, out);
}

// Round 11
// 20.284 us; speedup vs baseline: 1.3753x; 1.3753x over previous
//
#include <hip/hip_runtime.h>
#include <math.h>

#define DIMQ 16
#define HID  128
#define SPB  32          // samples per block (8 waves; each wave owns ONE 16-h tile, all samples)
#define NTHREADS 512

typedef __attribute__((ext_vector_type(8))) _Float16 f16x8;  // MFMA A/B frag (4 VGPRs)
typedef __attribute__((ext_vector_type(4))) _Float16 f16x4;  // packed b64 store
typedef __attribute__((ext_vector_type(4))) float f32x4;     // MFMA acc

// f16 row strides (elements)
#define ASTR 280         // ABT[16][280]: [A^T | B^T], 560B row -> bank skew
#define USTR 280         // usp[32][280]: u at h'=0..127, -sp at h'=128..255
#define SSTR 136         // sst[32][136]: s values (validated stride)

// LDS layout (bytes). Mscr overlays everything below it AFTER barrier #2.
#define OFF_WBF  0       // f16[128][32] = 8192
#define OFF_YBF  8192    // f16[32][32]  = 2048  -> 10240
#define OFF_ABT  10240   // f16[16][280] = 8960  -> 19200
#define OFF_USP  19200   // f16[32][280] = 17920 -> 37120
#define OFF_SST  37120   // f16[32][136] = 8704  -> 45824
#define OFF_B1   45824   // f32[128] -> 46336
#define OFF_W2   46336   // f32[128] -> 46848
#define OFF_MSCR 0       // f32 32*320 = 40960 (post-barrier-2 overlay)
#define LDS_BYTES 46848

// XOR-swizzle inside each sample's 320-f32 M-scratch (v7-validated).
__device__ __forceinline__ int mswz(int s, int off) {
    return s * 320 + (off ^ ((s & 7) << 2));
}

__global__ __launch_bounds__(NTHREADS, 4)
void lag_accel_kernel(const float* __restrict__ y,    // [BATCH][32]
                      const float* __restrict__ W1,   // [128][32]
                      const float* __restrict__ b1,   // [128]
                      const float* __restrict__ w2,   // [128]
                      float* __restrict__ out)        // [BATCH][16]
{
    __shared__ __align__(16) char smem[LDS_BYTES];
    _Float16* Wbf = (_Float16*)(smem + OFF_WBF);   // [128][32] f16 row-major W1
    _Float16* Ybf = (_Float16*)(smem + OFF_YBF);   // [32][32]  f16 sample-major y
    _Float16* ABT = (_Float16*)(smem + OFF_ABT);   // [16][280]: [j][h]=A[h][j], [j][128+h]=B[h][j]
    _Float16* usp = (_Float16*)(smem + OFF_USP);   // [32][280]: u / -sp
    _Float16* sst = (_Float16*)(smem + OFF_SST);   // [32][136]: s
    float* b1s = (float*)(smem + OFF_B1);
    float* w2s = (float*)(smem + OFF_W2);

    const int tid = threadIdx.x;
    const long long s0 = (long long)blockIdx.x * SPB;

    // ---- init staging: W1 (row-major f16 + transposed f16), y f16, b1, w2 ----
    for (int idx = tid; idx < HID * 32; idx += NTHREADS) {
        float v = W1[idx];
        int h = idx >> 5, k = idx & 31;
        _Float16 hv = (_Float16)v;
        Wbf[h * 32 + k] = hv;
        if (k < 16) ABT[k * ASTR + h] = hv;
        else        ABT[(k - 16) * ASTR + 128 + h] = hv;
    }
    for (int idx = tid; idx < SPB * 32; idx += NTHREADS)
        Ybf[idx] = (_Float16)y[s0 * 32 + idx];
    if (tid < HID) { b1s[tid] = b1[tid]; w2s[tid] = w2[tid]; }

    const int wave = tid >> 6;
    const int lane = tid & 63;
    const int grp  = lane >> 4;      // MFMA quadrant (k-slice / D row-block)
    const int j    = lane & 15;      // MFMA m/n index
    const int ht   = wave;           // this wave's h-tile (h = 16*ht .. 16*ht+15)

    __syncthreads();   // barrier 0: staging complete

    // ---- z/aqd GEMM: z = [A|B].y + b1 and aqd = [0|A].y (K=32), per h-tile ----
    f16x8 aW  = *(const f16x8*)&Wbf[(ht * 16 + j) * 32 + (grp << 3)];
    // [0|A] operand: Aop[h][k] = (k>=16) ? A[h][k-16] : 0.
    f16x8 aAl = *(const f16x8*)&Wbf[(ht * 16 + j) * 32 + ((grp & 1) << 3)];
    f16x8 aA;
#pragma unroll
    for (int e = 0; e < 8; ++e) aA[e] = (grp >= 2) ? aAl[e] : (_Float16)0.0f;

    float4 b1v = *(const float4*)&b1s[ht * 16 + (grp << 2)];
    float4 w2v = *(const float4*)&w2s[ht * 16 + (grp << 2)];

    f32x4 zacc[2], aacc[2];
    {
        f32x4 ci; ci[0] = b1v.x; ci[1] = b1v.y; ci[2] = b1v.z; ci[3] = b1v.w;
        f32x4 zf = {0.0f, 0.0f, 0.0f, 0.0f};
        f16x8 yf0 = *(const f16x8*)&Ybf[(0 * 16 + j) * 32 + (grp << 3)];
        f16x8 yf1 = *(const f16x8*)&Ybf[(1 * 16 + j) * 32 + (grp << 3)];
        zacc[0] = __builtin_amdgcn_mfma_f32_16x16x32_f16(aW, yf0, ci, 0, 0, 0);
        zacc[1] = __builtin_amdgcn_mfma_f32_16x16x32_f16(aW, yf1, ci, 0, 0, 0);
        aacc[0] = __builtin_amdgcn_mfma_f32_16x16x32_f16(aA, yf0, zf, 0, 0, 0);
        aacc[1] = __builtin_amdgcn_mfma_f32_16x16x32_f16(aA, yf1, zf, 0, 0, 0);
    }

    // ---- elementwise: t,u,s,sp per (h = 16ht+4grp+r, smp = 16st+j); stage f16 ----
    const int h4 = ht * 16 + (grp << 2);
#define EWST(st)                                                         \
    {                                                                    \
        _Float16 su[4], sn[4], sv[4];                                    \
        _Pragma("unroll")                                                \
        for (int r = 0; r < 4; ++r) {                                    \
            float z  = zacc[st][r], aq = aacc[st][r];                    \
            float w2c = (r == 0) ? w2v.x : (r == 1) ? w2v.y               \
                       : (r == 2) ? w2v.z : w2v.w;                       \
            float e  = __expf(2.0f * z);                                 \
            float rr = 2.0f * __builtin_amdgcn_rcpf(e + 1.0f);           \
            float t  = 1.0f - rr;                                        \
            float u  = w2c * (rr * (2.0f - rr));                         \
            float s  = -2.0f * t * u;                                    \
            float sp = s * aq;                                           \
            su[r] = (_Float16)u; sn[r] = (_Float16)(-sp);                \
            sv[r] = (_Float16)s;                                         \
        }                                                                \
        const int smp2 = (st) * 16 + j;                                  \
        f16x4 pa = {su[0], su[1], su[2], su[3]};                         \
        f16x4 pb = {sn[0], sn[1], sn[2], sn[3]};                         \
        f16x4 pc = {sv[0], sv[1], sv[2], sv[3]};                         \
        *(f16x4*)&usp[smp2 * USTR + h4]       = pa;                      \
        *(f16x4*)&usp[smp2 * USTR + 128 + h4] = pb;                      \
        *(f16x4*)&sst[smp2 * SSTR + h4]       = pc;                      \
    }
    EWST(0)
    EWST(1)
#undef EWST

    __syncthreads();   // barrier 1: u/-sp/s staged by all h-tiles

    // ---- rhs GEMM (waves 0,1): rhs = [A^T|B^T].[u;-sp], K=256; D lands in solve layout ----
    f32x4 racc = {0.0f, 0.0f, 0.0f, 0.0f};
    if (wave < 2) {
#pragma unroll
        for (int kc = 0; kc < 8; ++kc) {
            f16x8 af = *(const f16x8*)&ABT[j * ASTR + (kc << 5) + (grp << 3)];
            f16x8 bf = *(const f16x8*)&usp[(wave * 16 + j) * USTR + (kc << 5) + (grp << 3)];
            racc = __builtin_amdgcn_mfma_f32_16x16x32_f16(af, bf, racc, 0, 0, 0);
        }
    }

    // ---- M = I + B~^T diag(s) B~ via MFMA; afrag = s (*) B via v_pk_mul_f16 ----
    f32x4 acc[4];
    {
        f32x4 ident;
#pragma unroll
        for (int r = 0; r < 4; ++r) ident[r] = ((grp << 2) + r == j) ? 1.0f : 0.0f;
#pragma unroll
        for (int gs = 0; gs < 4; ++gs) acc[gs] = ident;
    }
#pragma unroll
    for (int kc = 0; kc < 4; ++kc) {
        f16x8 bfrag = *(const f16x8*)&ABT[j * ASTR + 128 + (kc << 5) + (grp << 3)];
#pragma unroll
        for (int gs = 0; gs < 4; ++gs) {
            f16x8 sfrag = *(const f16x8*)&sst[(wave * 4 + gs) * SSTR + (kc << 5) + (grp << 3)];
            f16x8 afrag = sfrag * bfrag;   // v_pk_mul_f16 x4 (was 24 cvt/mul ops in bf16)
            acc[gs] = __builtin_amdgcn_mfma_f32_16x16x32_f16(afrag, bfrag, acc[gs], 0, 0, 0);
        }
    }

    __syncthreads();   // barrier 2: all GEMM reads of Wbf/Ybf/ABT/usp/sst done -> Mscr overlay

    float* Mscr = (float*)(smem + OFF_MSCR);
    // M symmetric: D(rows 4grp..4grp+3, col j) == M[j][4grp..4grp+3] -> one b128/sample.
#pragma unroll
    for (int gs = 0; gs < 4; ++gs) {
        float4 v;
        v.x = acc[gs][0]; v.y = acc[gs][1]; v.z = acc[gs][2]; v.w = acc[gs][3];
        *(float4*)&Mscr[mswz(wave * 4 + gs, j * 20 + (grp << 2))] = v;
    }

    __syncthreads();   // barrier 3: scratch complete

    // ---- solve (waves 0,1; 16 samples each; 4 lanes/sample, 4 rows/lane) ----
    if (wave >= 2) return;
    const int sl = lane & 15;            // sample within this wave's half
    const int rb = lane >> 4;            // row block (rows 4rb..4rb+3)
    const int s  = wave * 16 + sl;       // sample within block

    float M4[4][16], r4[4], d4[4];
#pragma unroll
    for (int r = 0; r < 4; ++r) {
        const int ro = (4 * rb + r) * 20;
        float4 v0 = *(const float4*)&Mscr[mswz(s, ro + 0)];
        float4 v1 = *(const float4*)&Mscr[mswz(s, ro + 4)];
        float4 v2 = *(const float4*)&Mscr[mswz(s, ro + 8)];
        float4 v3 = *(const float4*)&Mscr[mswz(s, ro + 12)];
        M4[r][0]=v0.x; M4[r][1]=v0.y; M4[r][2]=v0.z; M4[r][3]=v0.w;
        M4[r][4]=v1.x; M4[r][5]=v1.y; M4[r][6]=v1.z; M4[r][7]=v1.w;
        M4[r][8]=v2.x; M4[r][9]=v2.y; M4[r][10]=v2.z; M4[r][11]=v2.w;
        M4[r][12]=v3.x; M4[r][13]=v3.y; M4[r][14]=v3.z; M4[r][15]=v3.w;
        r4[r] = racc[r];                 // rhs already in the right lane/reg
        d4[r] = 1.0f;
    }

    // Gauss-Jordan, non-normalizing, triangular skip (v7-validated).
#pragma unroll
    for (int k = 0; k < 16; ++k) {
        const int src = sl + ((k >> 2) << 4);
        float piv = __shfl(M4[k & 3][k], src, 64);
        float rk  = __shfl(r4[k & 3], src, 64);
        float invp = __builtin_amdgcn_rcpf(piv);
        invp = invp * (2.0f - piv * invp);
        float f[4];
#pragma unroll
        for (int r = 0; r < 4; ++r) {
            float fr = M4[r][k] * invp;
            const bool isk = ((rb << 2) + r) == k;
            f[r]  = isk ? 0.0f : fr;
            d4[r] = isk ? piv : d4[r];
            r4[r] = fmaf(-f[r], rk, r4[r]);
        }
#pragma unroll
        for (int i = k + 1; i < 16; ++i) {
            float p = __shfl(M4[k & 3][i], src, 64);
            M4[0][i] = fmaf(-f[0], p, M4[0][i]);
            M4[1][i] = fmaf(-f[1], p, M4[1][i]);
            M4[2][i] = fmaf(-f[2], p, M4[2][i]);
            M4[3][i] = fmaf(-f[3], p, M4[3][i]);
        }
    }

    float4 xo;
    {
        float i0 = __builtin_amdgcn_rcpf(d4[0]); i0 = i0 * (2.0f - d4[0] * i0);
        float i1 = __builtin_amdgcn_rcpf(d4[1]); i1 = i1 * (2.0f - d4[1] * i1);
        float i2 = __builtin_amdgcn_rcpf(d4[2]); i2 = i2 * (2.0f - d4[2] * i2);
        float i3 = __builtin_amdgcn_rcpf(d4[3]); i3 = i3 * (2.0f - d4[3] * i3);
        xo.x = r4[0] * i0; xo.y = r4[1] * i1; xo.z = r4[2] * i2; xo.w = r4[3] * i3;
    }
    *(float4*)&out[(s0 + s) * DIMQ + (rb << 2)] = xo;
}

extern "C" void kernel_launch(void* const* d_in, const int* in_sizes, int n_in,
                              void* d_out, int out_size, void* d_ws, size_t ws_size,
                              hipStream_t stream) {
    const float* y  = (const float*)d_in[0];
    const float* W1 = (const float*)d_in[1];
    const float* b1 = (const float*)d_in[2];
    const float* w2 = (const float*)d_in[3];
    float* out = (float*)d_out;
    const int batch = in_sizes[0] / 32;          // 32768
    const int blocks = (batch + SPB - 1) / SPB;  // 1024
    lag_accel_kernel<<<blocks, NTHREADS, 0, stream>>>(y, W1, b1, w2, out);
}